// Round 1
// baseline (7380.022 us; speedup 1.0000x reference)
//
#include <hip/hip_runtime.h>
#include <math.h>

#define NIN 64
#define NHID 128
#define NOUT 64
#define NB 16
#define NB2 16

__device__ __forceinline__ float sigmoidf(float x){ return 1.0f/(1.0f+expf(-x)); }

// ---------------- precompute: degree, dinv, CSR ----------------
__global__ void k_deg_init(int* __restrict__ deg, int n){
  int v = blockIdx.x*256 + threadIdx.x;
  if(v<n) deg[v] = 1; // self loop
}
__global__ void k_deg_count(const int* __restrict__ dst, int E, int* __restrict__ deg){
  int e = blockIdx.x*256 + threadIdx.x;
  if(e<E) atomicAdd(&deg[dst[e]], 1);
}
__global__ void k_dinv(const int* __restrict__ deg, float* __restrict__ dinv, int n){
  int v = blockIdx.x*256 + threadIdx.x;
  if(v<n) dinv[v] = rsqrtf((float)deg[v]);
}
__global__ __launch_bounds__(1024) void k_scan(const int* __restrict__ deg,
    int* __restrict__ row_ptr, int* __restrict__ fill, int n){
  __shared__ int lds[1024];
  __shared__ int s_carry;
  if(threadIdx.x==0) s_carry=0;
  __syncthreads();
  int nchunk=(n+1023)/1024;
  for(int ch=0; ch<nchunk; ++ch){
    int v = ch*1024 + threadIdx.x;
    int val = (v<n)? (deg[v]-1) : 0;   // edge count only (self loop excluded)
    lds[threadIdx.x]=val;
    __syncthreads();
    for(int off=1; off<1024; off<<=1){
      int t=(threadIdx.x>=off)? lds[threadIdx.x-off] : 0;
      __syncthreads();
      lds[threadIdx.x]+=t;
      __syncthreads();
    }
    int incl=lds[threadIdx.x];
    int carry=s_carry;
    if(v<n){ row_ptr[v]=carry+incl-val; fill[v]=carry+incl-val; }
    __syncthreads();
    if(threadIdx.x==1023) s_carry=carry+lds[1023];
    __syncthreads();
  }
  if(threadIdx.x==0) row_ptr[n]=s_carry;
}
__global__ void k_fill(const int* __restrict__ src, const int* __restrict__ dst, int E,
                       int* __restrict__ fill, int* __restrict__ col){
  int e = blockIdx.x*256 + threadIdx.x;
  if(e<E){
    int d = dst[e];
    int pos = atomicAdd(&fill[d], 1);
    col[pos] = src[e];
  }
}

// ---------------- weight prep (transpose/concat) ----------------
__global__ void k_prep_gates(const float* __restrict__ Wi, const float* __restrict__ Wf,
                             const float* __restrict__ Wo, const float* __restrict__ Wg,
                             float* __restrict__ Wt){
  int idx = blockIdx.x*256 + threadIdx.x;
  if(idx >= 192*512) return;
  int k = idx >> 9, j = idx & 511;
  float v;
  if(j<128)       v = Wi[j*192+k];
  else if(j<256)  v = Wf[(j-128)*192+k];
  else if(j<384)  v = Wo[(j-256)*192+k];
  else            v = Wg[(j-384)*192+k];
  Wt[idx] = v;
}
__global__ void k_prep_w1(const float* __restrict__ W1, float* __restrict__ W1t){
  int idx = blockIdx.x*256 + threadIdx.x;
  if(idx >= 128*256) return;
  int k = idx >> 8, j = idx & 255;
  W1t[idx] = (j<128)? W1[j*256+k] : W1[(j-128)*256+128+k];
}
__global__ void k_prep_wc(const float* __restrict__ Wc, float* __restrict__ Wct){
  int idx = blockIdx.x*256 + threadIdx.x;
  if(idx >= 128*64) return;
  int k = idx/64, j = idx%64;
  Wct[idx] = Wc[j*128+k];
}
__global__ void k_zero2(float* __restrict__ a, float* __restrict__ b, int sz){
  int i = blockIdx.x*256 + threadIdx.x;
  if(i<sz){ a[i]=0.0f; b[i]=0.0f; }
}

// ---------------- per-step: aggregation  agg = Anorm @ [xt, h] ----------------
__global__ __launch_bounds__(256) void k_agg(const float* __restrict__ xt,
    const float* __restrict__ h, const int* __restrict__ row_ptr,
    const int* __restrict__ col, const float* __restrict__ dinv,
    float* __restrict__ agg, int n){
  int wv = threadIdx.x >> 6, lane = threadIdx.x & 63;
  int v = blockIdx.x*4 + wv;
  if(v >= n) return;
  float dv = dinv[v];
  float wself = dv*dv;
  float a0 = wself * xt[(size_t)v*NIN + lane];
  float a1 = wself * h[(size_t)v*NHID + lane];
  float a2 = wself * h[(size_t)v*NHID + 64 + lane];
  int beg = row_ptr[v], end = row_ptr[v+1];
  for(int e=beg; e<end; ++e){
    int u = col[e];
    float w = dv * dinv[u];
    a0 = fmaf(w, xt[(size_t)u*NIN + lane], a0);
    a1 = fmaf(w, h[(size_t)u*NHID + lane], a1);
    a2 = fmaf(w, h[(size_t)u*NHID + 64 + lane], a2);
  }
  agg[(size_t)v*192 + lane]       = a0;
  agg[(size_t)v*192 + 64 + lane]  = a1;
  agg[(size_t)v*192 + 128 + lane] = a2;
}

// ---------------- per-step: gates GEMM + LSTM pointwise ----------------
__global__ __launch_bounds__(128) void k_lstm(const float* __restrict__ agg,
    const float* __restrict__ Wt, const float* __restrict__ bi, const float* __restrict__ bf,
    const float* __restrict__ bo, const float* __restrict__ bg,
    float* __restrict__ h, float* __restrict__ c, int n){
  __shared__ float s_agg[NB][192];
  int v0 = blockIdx.x*NB;
  for(int i=threadIdx.x; i<NB*192; i+=128){
    int m = i/192, k = i - m*192;
    int v = v0 + m;
    s_agg[m][k] = (v<n)? agg[(size_t)v*192 + k] : 0.0f;
  }
  __syncthreads();
  int j = threadIdx.x;
  float ai[NB], af[NB], ao[NB], ag[NB];
  #pragma unroll
  for(int m=0;m<NB;++m){ ai[m]=0.f; af[m]=0.f; ao[m]=0.f; ag[m]=0.f; }
  for(int k=0;k<192;++k){
    float wi = Wt[k*512 + j];
    float wf = Wt[k*512 + 128 + j];
    float wo = Wt[k*512 + 256 + j];
    float wg = Wt[k*512 + 384 + j];
    #pragma unroll
    for(int m=0;m<NB;++m){
      float a = s_agg[m][k];
      ai[m]=fmaf(wi,a,ai[m]); af[m]=fmaf(wf,a,af[m]);
      ao[m]=fmaf(wo,a,ao[m]); ag[m]=fmaf(wg,a,ag[m]);
    }
  }
  float Bi=bi[j], Bf=bf[j], Bo=bo[j], Bg=bg[j];
  for(int m=0;m<NB;++m){
    int v = v0 + m;
    if(v >= n) break;
    float I = sigmoidf(ai[m]+Bi);
    float F = sigmoidf(af[m]+Bf);
    float O = sigmoidf(ao[m]+Bo);
    float G = tanhf(ag[m]+Bg);
    float cn = F*c[(size_t)v*NHID+j] + I*G;
    c[(size_t)v*NHID+j] = cn;
    h[(size_t)v*NHID+j] = O*tanhf(cn);
  }
}

// ---------------- head: Hin/Hout = h @ [W1a;W1b].T ----------------
__global__ __launch_bounds__(256) void k_head1(const float* __restrict__ h,
    const float* __restrict__ W1t, float* __restrict__ Hio, int n){
  __shared__ float s_h[NB2][NHID];
  int v0 = blockIdx.x*NB2;
  for(int i=threadIdx.x; i<NB2*NHID; i+=256){
    int m = i/NHID, k = i - m*NHID;
    int v = v0 + m;
    s_h[m][k] = (v<n)? h[(size_t)v*NHID + k] : 0.0f;
  }
  __syncthreads();
  int j = threadIdx.x;  // 0..255: [0,128)=Hin, [128,256)=Hout
  float acc[NB2];
  #pragma unroll
  for(int m=0;m<NB2;++m) acc[m]=0.f;
  for(int k=0;k<NHID;++k){
    float w = W1t[k*256 + j];
    #pragma unroll
    for(int m=0;m<NB2;++m) acc[m] = fmaf(w, s_h[m][k], acc[m]);
  }
  for(int m=0;m<NB2;++m){
    int v = v0 + m;
    if(v >= n) break;
    Hio[(size_t)v*256 + j] = acc[m];
  }
}

// ---------------- edge relu + scatter to receiver ----------------
__global__ __launch_bounds__(256) void k_e2n(const float* __restrict__ Hio,
    const int* __restrict__ row_ptr, const int* __restrict__ col,
    const float* __restrict__ b1, float* __restrict__ nodes, int n){
  int wv = threadIdx.x >> 6, lane = threadIdx.x & 63;
  int v = blockIdx.x*4 + wv;
  if(v >= n) return;
  float base0 = Hio[(size_t)v*256 + lane]      + b1[lane];
  float base1 = Hio[(size_t)v*256 + 64 + lane] + b1[64+lane];
  float a0=0.f, a1=0.f;
  int beg=row_ptr[v], end=row_ptr[v+1];
  for(int e=beg; e<end; ++e){
    int u = col[e];
    float t0 = base0 + Hio[(size_t)u*256 + 128 + lane];
    float t1 = base1 + Hio[(size_t)u*256 + 192 + lane];
    a0 += fmaxf(t0, 0.0f);
    a1 += fmaxf(t1, 0.0f);
  }
  nodes[(size_t)v*NHID + lane]      = a0;
  nodes[(size_t)v*NHID + 64 + lane] = a1;
}

// ---------------- tmp = nodes @ Wc.T ----------------
__global__ __launch_bounds__(64) void k_head2(const float* __restrict__ nodes,
    const float* __restrict__ Wct, float* __restrict__ tmp, int n){
  __shared__ float s_n[16][NHID];
  int v0 = blockIdx.x*16;
  for(int i=threadIdx.x; i<16*NHID; i+=64){
    int m = i/NHID, k = i - m*NHID;
    int v = v0 + m;
    s_n[m][k] = (v<n)? nodes[(size_t)v*NHID + k] : 0.0f;
  }
  __syncthreads();
  int j = threadIdx.x; // 0..63
  float acc[16];
  #pragma unroll
  for(int m=0;m<16;++m) acc[m]=0.f;
  for(int k=0;k<NHID;++k){
    float w = Wct[k*64 + j];
    #pragma unroll
    for(int m=0;m<16;++m) acc[m] = fmaf(w, s_n[m][k], acc[m]);
  }
  for(int m=0;m<16;++m){
    int v = v0 + m;
    if(v >= n) break;
    tmp[(size_t)v*64 + j] = acc[m];
  }
}

// ---------------- out = Anorm @ tmp + bc ----------------
__global__ __launch_bounds__(256) void k_final(const float* __restrict__ tmp,
    const int* __restrict__ row_ptr, const int* __restrict__ col,
    const float* __restrict__ dinv, const float* __restrict__ bc,
    float* __restrict__ out, int n){
  int wv = threadIdx.x >> 6, lane = threadIdx.x & 63;
  int v = blockIdx.x*4 + wv;
  if(v >= n) return;
  float dv = dinv[v];
  float acc = dv*dv*tmp[(size_t)v*64 + lane];
  int beg=row_ptr[v], end=row_ptr[v+1];
  for(int e=beg; e<end; ++e){
    int u = col[e];
    acc = fmaf(dv*dinv[u], tmp[(size_t)u*64 + lane], acc);
  }
  out[(size_t)v*64 + lane] = acc + bc[lane];
}

extern "C" void kernel_launch(void* const* d_in, const int* in_sizes, int n_in,
                              void* d_out, int out_size, void* d_ws, size_t ws_size,
                              hipStream_t stream) {
  (void)n_in; (void)ws_size;
  const float* x  = (const float*)d_in[0];
  const int*   ei = (const int*)d_in[1];
  const float* Wi = (const float*)d_in[4];  const float* bi = (const float*)d_in[5];
  const float* Wf = (const float*)d_in[6];  const float* bf_ = (const float*)d_in[7];
  const float* Wo = (const float*)d_in[8];  const float* bo = (const float*)d_in[9];
  const float* Wg = (const float*)d_in[10]; const float* bg = (const float*)d_in[11];
  const float* W1 = (const float*)d_in[12]; const float* b1 = (const float*)d_in[13];
  const float* Wc = (const float*)d_in[14]; const float* bc = (const float*)d_in[15];
  float* out = (float*)d_out;

  const int E = in_sizes[2];
  const int n = out_size / NOUT;
  const int T = in_sizes[0] / (n * NIN);
  const int* src = ei;       // edge_index[0] = senders
  const int* dst = ei + E;   // edge_index[1] = receivers (== m_in)

  // workspace carve (256B aligned)
  char* p = (char*)d_ws;
  auto alloc = [&](size_t bytes){ char* r = p; p += ((bytes + 255)/256)*256; return r; };
  int*   deg     = (int*)  alloc((size_t)n*4);
  float* dinv    = (float*)alloc((size_t)n*4);
  int*   row_ptr = (int*)  alloc((size_t)(n+1)*4);
  int*   fill    = (int*)  alloc((size_t)n*4);
  int*   col     = (int*)  alloc((size_t)E*4);
  float* Wt      = (float*)alloc((size_t)192*512*4);
  float* W1t     = (float*)alloc((size_t)128*256*4);
  float* Wct     = (float*)alloc((size_t)128*64*4);
  float* h       = (float*)alloc((size_t)n*NHID*4);
  float* c       = (float*)alloc((size_t)n*NHID*4);
  float* agg     = (float*)alloc((size_t)n*192*4);
  float* Hio     = (float*)alloc((size_t)n*256*4);
  float* nodes   = (float*)alloc((size_t)n*NHID*4);
  float* tmp     = (float*)alloc((size_t)n*64*4);

  int gn  = (n+255)/256;
  int gE  = (E+255)/256;

  // graph structure
  k_deg_init <<<gn, 256, 0, stream>>>(deg, n);
  k_deg_count<<<gE, 256, 0, stream>>>(dst, E, deg);
  k_dinv     <<<gn, 256, 0, stream>>>(deg, dinv, n);
  k_scan     <<<1, 1024, 0, stream>>>(deg, row_ptr, fill, n);
  k_fill     <<<gE, 256, 0, stream>>>(src, dst, E, fill, col);

  // weights
  k_prep_gates<<<(192*512+255)/256, 256, 0, stream>>>(Wi, Wf, Wo, Wg, Wt);
  k_prep_w1   <<<(128*256+255)/256, 256, 0, stream>>>(W1, W1t);
  k_prep_wc   <<<(128*64+255)/256, 256, 0, stream>>>(Wc, Wct);

  // state init
  k_zero2<<<((n*NHID)+255)/256, 256, 0, stream>>>(h, c, n*NHID);

  // recurrent loop
  int gAgg  = (n+3)/4;
  int gLstm = (n+NB-1)/NB;
  for(int t=0; t<T; ++t){
    const float* xt = x + (size_t)t*n*NIN;
    k_agg <<<gAgg, 256, 0, stream>>>(xt, h, row_ptr, col, dinv, agg, n);
    k_lstm<<<gLstm, 128, 0, stream>>>(agg, Wt, bi, bf_, bo, bg, h, c, n);
  }

  // head
  k_head1<<<(n+NB2-1)/NB2, 256, 0, stream>>>(h, W1t, Hio, n);
  k_e2n  <<<(n+3)/4, 256, 0, stream>>>(Hio, row_ptr, col, b1, nodes, n);
  k_head2<<<(n+15)/16, 64, 0, stream>>>(nodes, Wct, tmp, n);
  k_final<<<(n+3)/4, 256, 0, stream>>>(tmp, row_ptr, col, dinv, bc, out, n);
}

// Round 2
// 3804.616 us; speedup vs baseline: 1.9398x; 1.9398x over previous
//
#include <hip/hip_runtime.h>
#include <math.h>

#define NIN 64
#define NHID 128
#define NOUT 64
#define MB 16      // nodes per block in step kernel
#define NB2 16

typedef __bf16 bf16x8 __attribute__((ext_vector_type(8)));
typedef float  floatx4 __attribute__((ext_vector_type(4)));

__device__ __forceinline__ float sigmoidf(float x){ return 1.0f/(1.0f+expf(-x)); }

// ---------------- precompute: degree, dinv, CSR ----------------
__global__ void k_deg_init(int* __restrict__ deg, int n){
  int v = blockIdx.x*256 + threadIdx.x;
  if(v<n) deg[v] = 1; // self loop
}
__global__ void k_deg_count(const int* __restrict__ dst, int E, int* __restrict__ deg){
  int e = blockIdx.x*256 + threadIdx.x;
  if(e<E) atomicAdd(&deg[dst[e]], 1);
}
__global__ void k_dinv(const int* __restrict__ deg, float* __restrict__ dinv, int n){
  int v = blockIdx.x*256 + threadIdx.x;
  if(v<n) dinv[v] = rsqrtf((float)deg[v]);
}
__global__ __launch_bounds__(1024) void k_scan(const int* __restrict__ deg,
    int* __restrict__ row_ptr, int* __restrict__ fill, int n){
  __shared__ int lds[1024];
  __shared__ int s_carry;
  if(threadIdx.x==0) s_carry=0;
  __syncthreads();
  int nchunk=(n+1023)/1024;
  for(int ch=0; ch<nchunk; ++ch){
    int v = ch*1024 + threadIdx.x;
    int val = (v<n)? (deg[v]-1) : 0;   // edge count only (self loop excluded)
    lds[threadIdx.x]=val;
    __syncthreads();
    for(int off=1; off<1024; off<<=1){
      int t=(threadIdx.x>=off)? lds[threadIdx.x-off] : 0;
      __syncthreads();
      lds[threadIdx.x]+=t;
      __syncthreads();
    }
    int incl=lds[threadIdx.x];
    int carry=s_carry;
    if(v<n){ row_ptr[v]=carry+incl-val; fill[v]=carry+incl-val; }
    __syncthreads();
    if(threadIdx.x==1023) s_carry=carry+lds[1023];
    __syncthreads();
  }
  if(threadIdx.x==0) row_ptr[n]=s_carry;
}
__global__ void k_fill(const int* __restrict__ src, const int* __restrict__ dst, int E,
                       int* __restrict__ fill, int* __restrict__ col){
  int e = blockIdx.x*256 + threadIdx.x;
  if(e<E){
    int d = dst[e];
    int pos = atomicAdd(&fill[d], 1);
    col[pos] = src[e];
  }
}

// ---------------- weight prep ----------------
// Wb: bf16, MFMA-B-fragment-ordered. Element ((CT*6+kt)*64 + L)*8 + jj holds
// B[k][colj] with colj = CT*16 + (L&15), k = kt*32 + (L>>4)*8 + jj,
// B[k][col] = Wgate[col&127][k], gate = col>>7 in order i,f,o,g.
__global__ void k_prep_wb(const float* __restrict__ Wi, const float* __restrict__ Wf,
                          const float* __restrict__ Wo, const float* __restrict__ Wg,
                          __bf16* __restrict__ Wb){
  int idx = blockIdx.x*256 + threadIdx.x;
  if(idx >= 32*6*64*8) return;
  int jj = idx & 7;
  int L  = (idx >> 3) & 63;
  int t  = idx >> 9;          // CT*6 + kt
  int kt = t - (t/6)*6, CT = t/6;
  int colj = CT*16 + (L & 15);
  int k    = kt*32 + ((L >> 4) << 3) + jj;
  int gate = colj >> 7, jg = colj & 127;
  const float* W = (gate==0)? Wi : (gate==1)? Wf : (gate==2)? Wo : Wg;
  Wb[idx] = (__bf16)W[jg*192 + k];
}
__global__ void k_prep_w1(const float* __restrict__ W1, float* __restrict__ W1t){
  int idx = blockIdx.x*256 + threadIdx.x;
  if(idx >= 128*256) return;
  int k = idx >> 8, j = idx & 255;
  W1t[idx] = (j<128)? W1[j*256+k] : W1[(j-128)*256+128+k];
}
__global__ void k_prep_wc(const float* __restrict__ Wc, float* __restrict__ Wct){
  int idx = blockIdx.x*256 + threadIdx.x;
  if(idx >= 128*64) return;
  int k = idx/64, j = idx%64;
  Wct[idx] = Wc[j*128+k];
}
__global__ void k_zero_state(float* __restrict__ c, __bf16* __restrict__ hA, int sz){
  int i = blockIdx.x*256 + threadIdx.x;
  if(i<sz){ c[i]=0.0f; hA[i]=(__bf16)0.0f; }
}

// ---------------- fused step: agg -> MFMA gates -> LSTM pointwise ----------------
// block = 256 threads = 4 waves, handles MB=16 nodes.
__global__ __launch_bounds__(256) void k_step(const float* __restrict__ xt,
    const __bf16* __restrict__ hprev, __bf16* __restrict__ hcur,
    float* __restrict__ hbuf, float* __restrict__ c,
    const int* __restrict__ row_ptr, const int* __restrict__ col,
    const float* __restrict__ dinv, const __bf16* __restrict__ Wb,
    const float* __restrict__ bi, const float* __restrict__ bf_,
    const float* __restrict__ bo, const float* __restrict__ bg, int n){
  __shared__ __bf16 s_a[6*512];        // A operand, fragment-ordered (6 KB)
  __shared__ float  s_pre[16*517];     // gate preacts, stride 517 (pad) (~32.3 KB)
  int tid = threadIdx.x, wv = tid>>6, l = tid&63;
  int v0 = blockIdx.x*MB;

  // ---- phase 1: aggregate 4 nodes per wave; lane l covers feature chunks ----
  for(int i=0;i<4;++i){
    int m = wv*4 + i;
    int v = v0 + m;
    float a0=0.f, a1=0.f, a2=0.f;
    if(v < n){
      float dv = dinv[v];
      float ws = dv*dv;
      a0 = ws * xt[(size_t)v*NIN + l];
      a1 = ws * (float)hprev[(size_t)v*NHID + l];
      a2 = ws * (float)hprev[(size_t)v*NHID + 64 + l];
      int beg = row_ptr[v], end = row_ptr[v+1];
      for(int e=beg; e<end; ++e){
        int u = col[e];
        float w = dv * dinv[u];
        a0 = fmaf(w, xt[(size_t)u*NIN + l], a0);
        a1 = fmaf(w, (float)hprev[(size_t)u*NHID + l], a1);
        a2 = fmaf(w, (float)hprev[(size_t)u*NHID + 64 + l], a2);
      }
    }
    // scatter into A-fragment order: elem (m,k) -> s_a[(kt*64 + ((k>>3)&3)*16 + m)*8 + (k&7)]
    int k0 = l;
    s_a[(((k0>>5))*64 + ((k0>>3)&3)*16 + m)*8 + (k0&7)] = (__bf16)a0;
    int k1 = 64 + l;
    s_a[(((k1>>5))*64 + ((k1>>3)&3)*16 + m)*8 + (k1&7)] = (__bf16)a1;
    int k2 = 128 + l;
    s_a[(((k2>>5))*64 + ((k2>>3)&3)*16 + m)*8 + (k2&7)] = (__bf16)a2;
  }
  __syncthreads();

  // ---- phase 2: wave wv computes gate wv (cols 128*wv..+128) via MFMA ----
  bf16x8 af[6];
  #pragma unroll
  for(int kt=0;kt<6;++kt) af[kt] = *(__shared__ bf16x8*)&s_a[(kt*64 + l)*8];
  #pragma unroll
  for(int ctl=0; ctl<8; ++ctl){
    int CT = wv*8 + ctl;
    floatx4 acc = {0.f,0.f,0.f,0.f};
    const __bf16* bp = Wb + (size_t)(CT*6)*512;
    #pragma unroll
    for(int kt=0;kt<6;++kt){
      bf16x8 bfr = *(const bf16x8*)(bp + kt*512 + l*8);
      acc = __builtin_amdgcn_mfma_f32_16x16x32_bf16(af[kt], bfr, acc, 0, 0, 0);
    }
    int j = CT*16 + (l&15);          // global col 0..511
    int mrow = (l>>4)*4;             // C/D layout: row = quad*4 + reg
    #pragma unroll
    for(int r=0;r<4;++r) s_pre[(mrow+r)*517 + j] = acc[r];
  }
  __syncthreads();

  // ---- phase 3: LSTM pointwise ----
  #pragma unroll
  for(int r=0;r<8;++r){
    int idx = r*256 + tid;
    int m = idx >> 7, j = idx & 127;
    int v = v0 + m;
    if(v >= n) continue;
    float I = sigmoidf(s_pre[m*517 + j]        + bi[j]);
    float F = sigmoidf(s_pre[m*517 + 128 + j]  + bf_[j]);
    float O = sigmoidf(s_pre[m*517 + 256 + j]  + bo[j]);
    float G = tanhf   (s_pre[m*517 + 384 + j]  + bg[j]);
    size_t off = (size_t)v*NHID + j;
    float cn = F*c[off] + I*G;
    c[off] = cn;
    float hn = O*tanhf(cn);
    hbuf[off] = hn;
    hcur[off] = (__bf16)hn;
  }
}

// ---------------- head: Hin/Hout = h @ [W1a;W1b].T ----------------
__global__ __launch_bounds__(256) void k_head1(const float* __restrict__ h,
    const float* __restrict__ W1t, float* __restrict__ Hio, int n){
  __shared__ float s_h[NB2][NHID];
  int v0 = blockIdx.x*NB2;
  for(int i=threadIdx.x; i<NB2*NHID; i+=256){
    int m = i/NHID, k = i - m*NHID;
    int v = v0 + m;
    s_h[m][k] = (v<n)? h[(size_t)v*NHID + k] : 0.0f;
  }
  __syncthreads();
  int j = threadIdx.x;  // 0..255: [0,128)=Hin, [128,256)=Hout
  float acc[NB2];
  #pragma unroll
  for(int m=0;m<NB2;++m) acc[m]=0.f;
  for(int k=0;k<NHID;++k){
    float w = W1t[k*256 + j];
    #pragma unroll
    for(int m=0;m<NB2;++m) acc[m] = fmaf(w, s_h[m][k], acc[m]);
  }
  for(int m=0;m<NB2;++m){
    int v = v0 + m;
    if(v >= n) break;
    Hio[(size_t)v*256 + j] = acc[m];
  }
}

// ---------------- edge relu + scatter to receiver ----------------
__global__ __launch_bounds__(256) void k_e2n(const float* __restrict__ Hio,
    const int* __restrict__ row_ptr, const int* __restrict__ col,
    const float* __restrict__ b1, float* __restrict__ nodes, int n){
  int wv = threadIdx.x >> 6, lane = threadIdx.x & 63;
  int v = blockIdx.x*4 + wv;
  if(v >= n) return;
  float base0 = Hio[(size_t)v*256 + lane]      + b1[lane];
  float base1 = Hio[(size_t)v*256 + 64 + lane] + b1[64+lane];
  float a0=0.f, a1=0.f;
  int beg=row_ptr[v], end=row_ptr[v+1];
  for(int e=beg; e<end; ++e){
    int u = col[e];
    float t0 = base0 + Hio[(size_t)u*256 + 128 + lane];
    float t1 = base1 + Hio[(size_t)u*256 + 192 + lane];
    a0 += fmaxf(t0, 0.0f);
    a1 += fmaxf(t1, 0.0f);
  }
  nodes[(size_t)v*NHID + lane]      = a0;
  nodes[(size_t)v*NHID + 64 + lane] = a1;
}

// ---------------- tmp = nodes @ Wc.T ----------------
__global__ __launch_bounds__(64) void k_head2(const float* __restrict__ nodes,
    const float* __restrict__ Wct, float* __restrict__ tmp, int n){
  __shared__ float s_n[16][NHID];
  int v0 = blockIdx.x*16;
  for(int i=threadIdx.x; i<16*NHID; i+=64){
    int m = i/NHID, k = i - m*NHID;
    int v = v0 + m;
    s_n[m][k] = (v<n)? nodes[(size_t)v*NHID + k] : 0.0f;
  }
  __syncthreads();
  int j = threadIdx.x; // 0..63
  float acc[16];
  #pragma unroll
  for(int m=0;m<16;++m) acc[m]=0.f;
  for(int k=0;k<NHID;++k){
    float w = Wct[k*64 + j];
    #pragma unroll
    for(int m=0;m<16;++m) acc[m] = fmaf(w, s_n[m][k], acc[m]);
  }
  for(int m=0;m<16;++m){
    int v = v0 + m;
    if(v >= n) break;
    tmp[(size_t)v*64 + j] = acc[m];
  }
}

// ---------------- out = Anorm @ tmp + bc ----------------
__global__ __launch_bounds__(256) void k_final(const float* __restrict__ tmp,
    const int* __restrict__ row_ptr, const int* __restrict__ col,
    const float* __restrict__ dinv, const float* __restrict__ bc,
    float* __restrict__ out, int n){
  int wv = threadIdx.x >> 6, lane = threadIdx.x & 63;
  int v = blockIdx.x*4 + wv;
  if(v >= n) return;
  float dv = dinv[v];
  float acc = dv*dv*tmp[(size_t)v*64 + lane];
  int beg=row_ptr[v], end=row_ptr[v+1];
  for(int e=beg; e<end; ++e){
    int u = col[e];
    acc = fmaf(dv*dinv[u], tmp[(size_t)u*64 + lane], acc);
  }
  out[(size_t)v*64 + lane] = acc + bc[lane];
}

extern "C" void kernel_launch(void* const* d_in, const int* in_sizes, int n_in,
                              void* d_out, int out_size, void* d_ws, size_t ws_size,
                              hipStream_t stream) {
  (void)n_in; (void)ws_size;
  const float* x  = (const float*)d_in[0];
  const int*   ei = (const int*)d_in[1];
  const float* Wi = (const float*)d_in[4];  const float* bi = (const float*)d_in[5];
  const float* Wf = (const float*)d_in[6];  const float* bf_ = (const float*)d_in[7];
  const float* Wo = (const float*)d_in[8];  const float* bo = (const float*)d_in[9];
  const float* Wg = (const float*)d_in[10]; const float* bg = (const float*)d_in[11];
  const float* W1 = (const float*)d_in[12]; const float* b1 = (const float*)d_in[13];
  const float* Wc = (const float*)d_in[14]; const float* bc = (const float*)d_in[15];
  float* out = (float*)d_out;

  const int E = in_sizes[2];
  const int n = out_size / NOUT;
  const int T = in_sizes[0] / (n * NIN);
  const int* src = ei;       // edge_index[0] = senders
  const int* dst = ei + E;   // edge_index[1] = receivers (== m_in)

  // workspace carve (256B aligned)
  char* p = (char*)d_ws;
  auto alloc = [&](size_t bytes){ char* r = p; p += ((bytes + 255)/256)*256; return r; };
  int*    deg     = (int*)   alloc((size_t)n*4);
  float*  dinv    = (float*) alloc((size_t)n*4);
  int*    row_ptr = (int*)   alloc((size_t)(n+1)*4);
  int*    fill    = (int*)   alloc((size_t)n*4);
  int*    col     = (int*)   alloc((size_t)E*4);
  __bf16* Wb      = (__bf16*)alloc((size_t)32*6*64*8*2);
  float*  W1t     = (float*) alloc((size_t)128*256*4);
  float*  Wct     = (float*) alloc((size_t)128*64*4);
  __bf16* hA      = (__bf16*)alloc((size_t)n*NHID*2);
  __bf16* hB      = (__bf16*)alloc((size_t)n*NHID*2);
  float*  hbuf    = (float*) alloc((size_t)n*NHID*4);
  float*  c       = (float*) alloc((size_t)n*NHID*4);
  float*  Hio     = (float*) alloc((size_t)n*256*4);
  float*  nodes   = (float*) alloc((size_t)n*NHID*4);
  float*  tmp     = (float*) alloc((size_t)n*64*4);

  int gn  = (n+255)/256;
  int gE  = (E+255)/256;

  // graph structure
  k_deg_init <<<gn, 256, 0, stream>>>(deg, n);
  k_deg_count<<<gE, 256, 0, stream>>>(dst, E, deg);
  k_dinv     <<<gn, 256, 0, stream>>>(deg, dinv, n);
  k_scan     <<<1, 1024, 0, stream>>>(deg, row_ptr, fill, n);
  k_fill     <<<gE, 256, 0, stream>>>(src, dst, E, fill, col);

  // weights
  k_prep_wb<<<(32*6*64*8+255)/256, 256, 0, stream>>>(Wi, Wf, Wo, Wg, Wb);
  k_prep_w1<<<(128*256+255)/256, 256, 0, stream>>>(W1, W1t);
  k_prep_wc<<<(128*64+255)/256, 256, 0, stream>>>(Wc, Wct);

  // state init
  k_zero_state<<<((n*NHID)+255)/256, 256, 0, stream>>>(c, hA, n*NHID);

  // recurrent loop: one fused kernel per step
  int gStep = (n + MB - 1)/MB;
  for(int t=0; t<T; ++t){
    const float* xt = x + (size_t)t*n*NIN;
    const __bf16* hp = (t & 1)? hB : hA;
    __bf16*       hc = (t & 1)? hA : hB;
    k_step<<<gStep, 256, 0, stream>>>(xt, hp, hc, hbuf, c, row_ptr, col, dinv,
                                      Wb, bi, bf_, bo, bg, n);
  }

  // head
  k_head1<<<(n+NB2-1)/NB2, 256, 0, stream>>>(hbuf, W1t, Hio, n);
  k_e2n  <<<(n+3)/4, 256, 0, stream>>>(Hio, row_ptr, col, b1, nodes, n);
  k_head2<<<(n+15)/16, 64, 0, stream>>>(nodes, Wct, tmp, n);
  k_final<<<(n+3)/4, 256, 0, stream>>>(tmp, row_ptr, col, dinv, bc, out, n);
}

// Round 4
// 3720.892 us; speedup vs baseline: 1.9834x; 1.0225x over previous
//
#include <hip/hip_runtime.h>
#include <math.h>

#define NIN 64
#define NHID 128
#define NOUT 64
#define MB 16
#define NB2 16
#define SPRE 516   // s_pre row stride (words); %32==4 -> <=2-way conflicts

typedef __bf16 bf16x8 __attribute__((ext_vector_type(8)));
typedef float  floatx4 __attribute__((ext_vector_type(4)));

__device__ __forceinline__ float sigmoidf(float x){ return 1.0f/(1.0f+expf(-x)); }
__device__ __forceinline__ float b2f_lo(unsigned p){ unsigned b = p<<16; return __uint_as_float(b); }
__device__ __forceinline__ float b2f_hi(unsigned p){ unsigned b = p & 0xffff0000u; return __uint_as_float(b); }
__device__ __forceinline__ unsigned f2pk(float lo, float hi){
  __bf16 a=(__bf16)lo, b=(__bf16)hi;
  unsigned short ua, ub;
  __builtin_memcpy(&ua,&a,2); __builtin_memcpy(&ub,&b,2);
  return (unsigned)ua | ((unsigned)ub<<16);
}

// ---------------- precompute: degree, dinv, CSR ----------------
__global__ void k_deg_init(int* __restrict__ deg, int n){
  int v = blockIdx.x*256 + threadIdx.x;
  if(v<n) deg[v] = 1;
}
__global__ void k_deg_count(const int* __restrict__ dst, int E, int* __restrict__ deg){
  int e = blockIdx.x*256 + threadIdx.x;
  if(e<E) atomicAdd(&deg[dst[e]], 1);
}
__global__ void k_dinv(const int* __restrict__ deg, float* __restrict__ dinv, int n){
  int v = blockIdx.x*256 + threadIdx.x;
  if(v<n) dinv[v] = rsqrtf((float)deg[v]);
}
__global__ __launch_bounds__(1024) void k_scan(const int* __restrict__ deg,
    int* __restrict__ row_ptr, int* __restrict__ fill, int n){
  __shared__ int lds[1024];
  __shared__ int s_carry;
  if(threadIdx.x==0) s_carry=0;
  __syncthreads();
  int nchunk=(n+1023)/1024;
  for(int ch=0; ch<nchunk; ++ch){
    int v = ch*1024 + threadIdx.x;
    int val = (v<n)? (deg[v]-1) : 0;
    lds[threadIdx.x]=val;
    __syncthreads();
    for(int off=1; off<1024; off<<=1){
      int t=(threadIdx.x>=off)? lds[threadIdx.x-off] : 0;
      __syncthreads();
      lds[threadIdx.x]+=t;
      __syncthreads();
    }
    int incl=lds[threadIdx.x];
    int carry=s_carry;
    if(v<n){ row_ptr[v]=carry+incl-val; fill[v]=carry+incl-val; }
    __syncthreads();
    if(threadIdx.x==1023) s_carry=carry+lds[1023];
    __syncthreads();
  }
  if(threadIdx.x==0) row_ptr[n]=s_carry;
}
__global__ void k_fill(const int* __restrict__ src, const int* __restrict__ dst, int E,
                       int* __restrict__ fill, int* __restrict__ col){
  int e = blockIdx.x*256 + threadIdx.x;
  if(e<E){
    int d = dst[e];
    int pos = atomicAdd(&fill[d], 1);
    col[pos] = src[e];
  }
}

// ---------------- weight prep ----------------
__global__ void k_prep_wb(const float* __restrict__ Wi, const float* __restrict__ Wf,
                          const float* __restrict__ Wo, const float* __restrict__ Wg,
                          __bf16* __restrict__ Wb){
  int idx = blockIdx.x*256 + threadIdx.x;
  if(idx >= 32*6*64*8) return;
  int jj = idx & 7;
  int L  = (idx >> 3) & 63;
  int t  = idx >> 9;
  int kt = t - (t/6)*6, CT = t/6;
  int colj = CT*16 + (L & 15);
  int k    = kt*32 + ((L >> 4) << 3) + jj;
  int gate = colj >> 7, jg = colj & 127;
  const float* W = (gate==0)? Wi : (gate==1)? Wf : (gate==2)? Wo : Wg;
  Wb[idx] = (__bf16)W[jg*192 + k];
}
__global__ void k_prep_w1(const float* __restrict__ W1, float* __restrict__ W1t){
  int idx = blockIdx.x*256 + threadIdx.x;
  if(idx >= 128*256) return;
  int k = idx >> 8, j = idx & 255;
  W1t[idx] = (j<128)? W1[j*256+k] : W1[(j-128)*256+128+k];
}
__global__ void k_prep_wc(const float* __restrict__ Wc, float* __restrict__ Wct){
  int idx = blockIdx.x*256 + threadIdx.x;
  if(idx >= 128*64) return;
  int k = idx/64, j = idx%64;
  Wct[idx] = Wc[j*128+k];
}
__global__ void k_zero_state(float2* __restrict__ cpack, unsigned* __restrict__ hpA, int sz){
  int i = blockIdx.x*256 + threadIdx.x;
  if(i<sz){ cpack[i]=make_float2(0.f,0.f); hpA[i]=0u; }
}

// ---------------- xs = dinv[v] * x, bf16 ----------------
__global__ void k_xscale(const float* __restrict__ x, const float* __restrict__ dinv,
                         __bf16* __restrict__ xs, int n, int total){
  int i = blockIdx.x*256 + threadIdx.x;
  if(i>=total) return;
  int row = i >> 6;          // t*n + v
  int v = row - (row/n)*n;
  xs[i] = (__bf16)(x[i]*dinv[v]);
}

// ---------------- xagg = Anorm @ x for ALL steps, stored in A-frag order ----
__global__ __launch_bounds__(256) void k_xagg(const __bf16* __restrict__ xs,
    const int* __restrict__ row_ptr, const int* __restrict__ col,
    const float* __restrict__ dinv, __bf16* __restrict__ xfrag, int n, int ntiles){
  __shared__ __bf16 s_f[1024];
  int t = blockIdx.y, tile = blockIdx.x;
  const __bf16* xst = xs + (size_t)t*n*64;
  int tid=threadIdx.x, wv=tid>>6, l=tid&63;
  int v0 = tile*MB;
  float a[4]; int e[4], en[4]; float dvv[4];
  #pragma unroll
  for(int i=0;i<4;++i){
    int v = v0 + wv*4 + i;
    bool ok = v<n;
    e[i]  = ok? row_ptr[v]   : 0;
    en[i] = ok? row_ptr[v+1] : 0;
    dvv[i]= ok? dinv[v] : 0.f;
    a[i]  = ok? (float)xst[(size_t)v*64 + l] : 0.f;
  }
  for(;;){
    bool any=false; float val[4];
    #pragma unroll
    for(int i=0;i<4;++i){
      val[i] = 0.f;
      if(e[i]<en[i]){ int u = col[e[i]]; val[i] = (float)xst[(size_t)u*64 + l]; e[i]++; any=true; }
    }
    if(!any) break;
    #pragma unroll
    for(int i=0;i<4;++i) a[i] += val[i];
  }
  #pragma unroll
  for(int i=0;i<4;++i){
    int m = wv*4 + i;
    s_f[(l>>5)*512 + ((l>>3)&3)*128 + m*8 + (l&7)] = (__bf16)(dvv[i]*a[i]);
  }
  __syncthreads();
  const unsigned* sw = (const unsigned*)s_f;
  unsigned* dstp = (unsigned*)(xfrag + ((size_t)t*ntiles + tile)*1024);
  dstp[tid] = sw[tid];
  dstp[256+tid] = sw[256+tid];
}

// ---------------- fused step ----------------
__global__ __launch_bounds__(256) void k_step(const __bf16* __restrict__ xfrag_t,
    const unsigned* __restrict__ hp_prev, unsigned* __restrict__ hp_cur,
    float* __restrict__ hbuf, float2* __restrict__ cpack,
    const int* __restrict__ row_ptr, const int* __restrict__ col,
    const float* __restrict__ dinv, const __bf16* __restrict__ Wb,
    const float* __restrict__ bi, const float* __restrict__ bf_,
    const float* __restrict__ bo, const float* __restrict__ bg, int n, int last){
  __shared__ __align__(16) __bf16 s_a[4*544];
  __shared__ float s_pre[16*SPRE];
  int tid = threadIdx.x, wv = tid>>6, l = tid&63;
  int v0 = blockIdx.x*MB;

  // x fragments straight from global — PER-TILE offset (R3 bug fix)
  const __bf16* xb = xfrag_t + (size_t)blockIdx.x*1024;
  bf16x8 afx0 = *(const bf16x8*)(xb + (size_t)l*8);
  bf16x8 afx1 = *(const bf16x8*)(xb + 512 + (size_t)l*8);

  // ---- phase 1: h aggregation, 4 nodes/wave, interleaved edges ----
  float a1[4], a2[4]; int e[4], en[4]; float dvv[4];
  #pragma unroll
  for(int i=0;i<4;++i){
    int v = v0 + wv*4 + i;
    bool ok = v<n;
    e[i]  = ok? row_ptr[v]   : 0;
    en[i] = ok? row_ptr[v+1] : 0;
    dvv[i]= ok? dinv[v] : 0.f;
    unsigned p = ok? hp_prev[(size_t)v*64 + l] : 0u;
    a1[i] = b2f_lo(p); a2[i] = b2f_hi(p);
  }
  for(;;){
    bool any=false; unsigned pk[4];
    #pragma unroll
    for(int i=0;i<4;++i){
      pk[i] = 0u;
      if(e[i]<en[i]){ int u = col[e[i]]; pk[i] = hp_prev[(size_t)u*64 + l]; e[i]++; any=true; }
    }
    if(!any) break;
    #pragma unroll
    for(int i=0;i<4;++i){ a1[i] += b2f_lo(pk[i]); a2[i] += b2f_hi(pk[i]); }
  }
  {
    int ktr = l>>5, quad = (l>>3)&3, jj = l&7;
    #pragma unroll
    for(int i=0;i<4;++i){
      int m = wv*4 + i;
      s_a[ktr*544     + quad*136 + m*8 + jj] = (__bf16)(dvv[i]*a1[i]);
      s_a[(2+ktr)*544 + quad*136 + m*8 + jj] = (__bf16)(dvv[i]*a2[i]);
    }
  }
  __syncthreads();

  // ---- phase 2: MFMA gates, wave wv = gate wv, bias in acc init ----
  bf16x8 afh[4];
  #pragma unroll
  for(int kt=0;kt<4;++kt)
    afh[kt] = *(__shared__ bf16x8*)&s_a[kt*544 + (l>>4)*136 + (l&15)*8];
  const float* bsel = (wv==0)? bi : (wv==1)? bf_ : (wv==2)? bo : bg;
  #pragma unroll
  for(int ctl=0; ctl<8; ++ctl){
    int CT = wv*8 + ctl;
    float b = bsel[ctl*16 + (l&15)];
    floatx4 acc = {b,b,b,b};
    const __bf16* bp = Wb + (size_t)(CT*6)*512;
    acc = __builtin_amdgcn_mfma_f32_16x16x32_bf16(afx0,   *(const bf16x8*)(bp        + (size_t)l*8), acc, 0,0,0);
    acc = __builtin_amdgcn_mfma_f32_16x16x32_bf16(afx1,   *(const bf16x8*)(bp + 512  + (size_t)l*8), acc, 0,0,0);
    acc = __builtin_amdgcn_mfma_f32_16x16x32_bf16(afh[0], *(const bf16x8*)(bp + 1024 + (size_t)l*8), acc, 0,0,0);
    acc = __builtin_amdgcn_mfma_f32_16x16x32_bf16(afh[1], *(const bf16x8*)(bp + 1536 + (size_t)l*8), acc, 0,0,0);
    acc = __builtin_amdgcn_mfma_f32_16x16x32_bf16(afh[2], *(const bf16x8*)(bp + 2048 + (size_t)l*8), acc, 0,0,0);
    acc = __builtin_amdgcn_mfma_f32_16x16x32_bf16(afh[3], *(const bf16x8*)(bp + 2560 + (size_t)l*8), acc, 0,0,0);
    int j = CT*16 + (l&15);
    int mrow = (l>>4)*4;
    #pragma unroll
    for(int r=0;r<4;++r) s_pre[(mrow+r)*SPRE + j] = acc[r];
  }
  __syncthreads();

  // ---- phase 3: LSTM pointwise ----
  #pragma unroll
  for(int it=0; it<4; ++it){
    int m = it*4 + (tid>>6);
    int v = v0 + m;
    if(v >= n) continue;
    float dv = dinv[v];
    const float* row = &s_pre[m*SPRE];
    float i1 = sigmoidf(row[l]);
    float f1 = sigmoidf(row[128+l]);
    float o1 = sigmoidf(row[256+l]);
    float g1 = tanhf  (row[384+l]);
    float i2 = sigmoidf(row[64+l]);
    float f2 = sigmoidf(row[192+l]);
    float o2 = sigmoidf(row[320+l]);
    float g2 = tanhf  (row[448+l]);
    size_t off = (size_t)v*64 + l;
    float2 cc = cpack[off];
    float c1 = f1*cc.x + i1*g1;
    float c2 = f2*cc.y + i2*g2;
    cpack[off] = make_float2(c1,c2);
    float h1 = o1*tanhf(c1), h2 = o2*tanhf(c2);
    hp_cur[off] = f2pk(dv*h1, dv*h2);
    if(last){
      hbuf[(size_t)v*NHID + l]      = h1;
      hbuf[(size_t)v*NHID + 64 + l] = h2;
    }
  }
}

// ---------------- head ----------------
__global__ __launch_bounds__(256) void k_head1(const float* __restrict__ h,
    const float* __restrict__ W1t, float* __restrict__ Hio, int n){
  __shared__ float s_h[NB2][NHID];
  int v0 = blockIdx.x*NB2;
  for(int i=threadIdx.x; i<NB2*NHID; i+=256){
    int m = i/NHID, k = i - m*NHID;
    int v = v0 + m;
    s_h[m][k] = (v<n)? h[(size_t)v*NHID + k] : 0.0f;
  }
  __syncthreads();
  int j = threadIdx.x;
  float acc[NB2];
  #pragma unroll
  for(int m=0;m<NB2;++m) acc[m]=0.f;
  for(int k=0;k<NHID;++k){
    float w = W1t[k*256 + j];
    #pragma unroll
    for(int m=0;m<NB2;++m) acc[m] = fmaf(w, s_h[m][k], acc[m]);
  }
  for(int m=0;m<NB2;++m){
    int v = v0 + m;
    if(v >= n) break;
    Hio[(size_t)v*256 + j] = acc[m];
  }
}
__global__ __launch_bounds__(256) void k_e2n(const float* __restrict__ Hio,
    const int* __restrict__ row_ptr, const int* __restrict__ col,
    const float* __restrict__ b1, float* __restrict__ nodes, int n){
  int wv = threadIdx.x >> 6, lane = threadIdx.x & 63;
  int v = blockIdx.x*4 + wv;
  if(v >= n) return;
  float base0 = Hio[(size_t)v*256 + lane]      + b1[lane];
  float base1 = Hio[(size_t)v*256 + 64 + lane] + b1[64+lane];
  float a0=0.f, a1=0.f;
  int beg=row_ptr[v], end=row_ptr[v+1];
  for(int e=beg; e<end; ++e){
    int u = col[e];
    float t0 = base0 + Hio[(size_t)u*256 + 128 + lane];
    float t1 = base1 + Hio[(size_t)u*256 + 192 + lane];
    a0 += fmaxf(t0, 0.0f);
    a1 += fmaxf(t1, 0.0f);
  }
  nodes[(size_t)v*NHID + lane]      = a0;
  nodes[(size_t)v*NHID + 64 + lane] = a1;
}
__global__ __launch_bounds__(64) void k_head2(const float* __restrict__ nodes,
    const float* __restrict__ Wct, float* __restrict__ tmp, int n){
  __shared__ float s_n[16][NHID];
  int v0 = blockIdx.x*16;
  for(int i=threadIdx.x; i<16*NHID; i+=64){
    int m = i/NHID, k = i - m*NHID;
    int v = v0 + m;
    s_n[m][k] = (v<n)? nodes[(size_t)v*NHID + k] : 0.0f;
  }
  __syncthreads();
  int j = threadIdx.x;
  float acc[16];
  #pragma unroll
  for(int m=0;m<16;++m) acc[m]=0.f;
  for(int k=0;k<NHID;++k){
    float w = Wct[k*64 + j];
    #pragma unroll
    for(int m=0;m<16;++m) acc[m] = fmaf(w, s_n[m][k], acc[m]);
  }
  for(int m=0;m<16;++m){
    int v = v0 + m;
    if(v >= n) break;
    tmp[(size_t)v*64 + j] = acc[m];
  }
}
__global__ __launch_bounds__(256) void k_final(const float* __restrict__ tmp,
    const int* __restrict__ row_ptr, const int* __restrict__ col,
    const float* __restrict__ dinv, const float* __restrict__ bc,
    float* __restrict__ out, int n){
  int wv = threadIdx.x >> 6, lane = threadIdx.x & 63;
  int v = blockIdx.x*4 + wv;
  if(v >= n) return;
  float dv = dinv[v];
  float acc = dv*dv*tmp[(size_t)v*64 + lane];
  int beg=row_ptr[v], end=row_ptr[v+1];
  for(int e=beg; e<end; ++e){
    int u = col[e];
    acc = fmaf(dv*dinv[u], tmp[(size_t)u*64 + lane], acc);
  }
  out[(size_t)v*64 + lane] = acc + bc[lane];
}

extern "C" void kernel_launch(void* const* d_in, const int* in_sizes, int n_in,
                              void* d_out, int out_size, void* d_ws, size_t ws_size,
                              hipStream_t stream) {
  (void)n_in; (void)ws_size;
  const float* x  = (const float*)d_in[0];
  const int*   ei = (const int*)d_in[1];
  const float* Wi = (const float*)d_in[4];  const float* bi = (const float*)d_in[5];
  const float* Wf = (const float*)d_in[6];  const float* bf_ = (const float*)d_in[7];
  const float* Wo = (const float*)d_in[8];  const float* bo = (const float*)d_in[9];
  const float* Wg = (const float*)d_in[10]; const float* bg = (const float*)d_in[11];
  const float* W1 = (const float*)d_in[12]; const float* b1 = (const float*)d_in[13];
  const float* Wc = (const float*)d_in[14]; const float* bc = (const float*)d_in[15];
  float* out = (float*)d_out;

  const int E = in_sizes[2];
  const int n = out_size / NOUT;
  const int T = in_sizes[0] / (n * NIN);
  const int ntiles = (n + MB - 1)/MB;
  const int* src = ei;
  const int* dst = ei + E;

  char* p = (char*)d_ws;
  auto alloc = [&](size_t bytes){ char* r = p; p += ((bytes + 255)/256)*256; return r; };
  int*      deg     = (int*)     alloc((size_t)n*4);
  float*    dinv    = (float*)   alloc((size_t)n*4);
  int*      row_ptr = (int*)     alloc((size_t)(n+1)*4);
  int*      fill    = (int*)     alloc((size_t)n*4);
  int*      col     = (int*)     alloc((size_t)E*4);
  __bf16*   Wb      = (__bf16*)  alloc((size_t)32*6*64*8*2);
  float*    W1t     = (float*)   alloc((size_t)128*256*4);
  float*    Wct     = (float*)   alloc((size_t)128*64*4);
  __bf16*   xs      = (__bf16*)  alloc((size_t)T*n*64*2);
  __bf16*   xfrag   = (__bf16*)  alloc((size_t)T*ntiles*1024*2);
  unsigned* hpA     = (unsigned*)alloc((size_t)n*64*4);
  unsigned* hpB     = (unsigned*)alloc((size_t)n*64*4);
  float*    hbuf    = (float*)   alloc((size_t)n*NHID*4);
  float2*   cpack   = (float2*)  alloc((size_t)n*64*8);
  float*    Hio     = (float*)   alloc((size_t)n*256*4);
  float*    nodes   = (float*)   alloc((size_t)n*NHID*4);
  float*    tmp     = (float*)   alloc((size_t)n*64*4);

  int gn = (n+255)/256;
  int gE = (E+255)/256;

  k_deg_init <<<gn, 256, 0, stream>>>(deg, n);
  k_deg_count<<<gE, 256, 0, stream>>>(dst, E, deg);
  k_dinv     <<<gn, 256, 0, stream>>>(deg, dinv, n);
  k_scan     <<<1, 1024, 0, stream>>>(deg, row_ptr, fill, n);
  k_fill     <<<gE, 256, 0, stream>>>(src, dst, E, fill, col);

  k_prep_wb<<<(32*6*64*8+255)/256, 256, 0, stream>>>(Wi, Wf, Wo, Wg, Wb);
  k_prep_w1<<<(128*256+255)/256, 256, 0, stream>>>(W1, W1t);
  k_prep_wc<<<(128*64+255)/256, 256, 0, stream>>>(Wc, Wct);

  int total = T*n*64;
  k_xscale<<<(total+255)/256, 256, 0, stream>>>(x, dinv, xs, n, total);
  k_xagg  <<<dim3(ntiles, T), 256, 0, stream>>>(xs, row_ptr, col, dinv, xfrag, n, ntiles);

  k_zero_state<<<((n*64)+255)/256, 256, 0, stream>>>(cpack, hpA, n*64);

  for(int t=0; t<T; ++t){
    const __bf16* xft = xfrag + ((size_t)t*ntiles)*1024;
    const unsigned* hp = (t & 1)? hpB : hpA;
    unsigned*       hc = (t & 1)? hpA : hpB;
    k_step<<<ntiles, 256, 0, stream>>>(xft, hp, hc, hbuf, cpack, row_ptr, col, dinv,
                                       Wb, bi, bf_, bo, bg, n, (t==T-1)?1:0);
  }

  k_head1<<<(n+NB2-1)/NB2, 256, 0, stream>>>(hbuf, W1t, Hio, n);
  k_e2n  <<<(n+3)/4, 256, 0, stream>>>(Hio, row_ptr, col, b1, nodes, n);
  k_head2<<<(n+15)/16, 64, 0, stream>>>(nodes, Wct, tmp, n);
  k_final<<<(n+3)/4, 256, 0, stream>>>(tmp, row_ptr, col, dinv, bc, out, n);
}